// Round 6
// baseline (700.106 us; speedup 1.0000x reference)
//
#include <hip/hip_runtime.h>

#define BATCHN 256
#define TSTEPS 199          // MAX_STEP - 1
#define NQ     1000
#define NROWS  (BATCHN * TSTEPS)   // 50944
#define RPB    4                   // rows (waves) per block
#define NBLOCKS (NROWS / RPB)      // 12736, exact

// ws layout (floats): [0..255] masked bce sum per batch, [256..511] masked row count per batch
__global__ void zero_ws_kernel(float* __restrict__ ws) {
    int i = threadIdx.x;
    if (i < 2 * BATCHN) ws[i] = 0.0f;
}

typedef float f4v __attribute__((ext_vector_type(4)));

// Unaligned (4B-aligned) 16B vector load; gfx950 supports unaligned global access,
// clang lowers this to global_load_dwordx4 without a 16B alignment assumption.
__device__ __forceinline__ f4v loadu4(const float* p) {
    f4v v; __builtin_memcpy(&v, p, 16); return v;
}

// One wave per row, SHIFTED loads: body groups are output-aligned from the start
// (elements 3+4*kp .. 6+4*kp, kp = lane + 64j, kp=0..248), so stores are straight
// register -> aligned float4 with ZERO cross-lane ops. Head e0..2 / tail e999 are
// handled by lanes 57..60 (idle in the j=3 group). BCE/mask are order-independent,
// so the shifted grouping changes nothing semantically.
__global__ __launch_bounds__(256) void main_kernel(
    const float* __restrict__ pred,
    const float* __restrict__ batch,
    float* __restrict__ out,
    float* __restrict__ ws)
{
    const int wid  = threadIdx.x >> 6;
    const int lane = threadIdx.x & 63;
    const int r = blockIdx.x * RPB + wid;      // row 0..NROWS-1
    const int b = r / TSTEPS;
    const int t = r - b * TSTEPS;

    const float* prow = pred + (size_t)r * NQ;
    const float* grow = batch + ((size_t)b * 200 + t + 1) * NQ;

    const bool f3 = lane < 57;                 // kp3 = lane+192 <= 248
    // extra element for lanes idle in group 3: 57->999, 58..60 -> 0..2
    const int e = (lane == 57) ? 999 : (lane >= 58 && lane < 61) ? (lane - 58) : -1;

    const f4v z = {0.f, 0.f, 0.f, 0.f};

    // g first (ballot dependency), then p — all loads issued before any compute
    f4v g0 = loadu4(grow + 3 + 4 * lane);
    f4v g1 = loadu4(grow + 3 + 4 * (lane + 64));
    f4v g2 = loadu4(grow + 3 + 4 * (lane + 128));
    f4v g3 = f3 ? loadu4(grow + 3 + 4 * (lane + 192)) : z;
    float gx = (e >= 0) ? grow[e] : 0.0f;

    f4v p0 = loadu4(prow + 3 + 4 * lane);
    f4v p1 = loadu4(prow + 3 + 4 * (lane + 64));
    f4v p2 = loadu4(prow + 3 + 4 * (lane + 128));
    f4v p3 = f3 ? loadu4(prow + 3 + 4 * (lane + 192)) : z;
    float px = (e >= 0) ? prow[e] : 0.0f;

    int any = (g0.x == 1.0f) | (g0.y == 1.0f) | (g0.z == 1.0f) | (g0.w == 1.0f)
            | (g1.x == 1.0f) | (g1.y == 1.0f) | (g1.z == 1.0f) | (g1.w == 1.0f)
            | (g2.x == 1.0f) | (g2.y == 1.0f) | (g2.z == 1.0f) | (g2.w == 1.0f)
            | (g3.x == 1.0f) | (g3.y == 1.0f) | (g3.z == 1.0f) | (g3.w == 1.0f)
            | (gx   == 1.0f);
    const unsigned long long bm = __ballot(any);
    const float m = bm ? 1.0f : 0.0f;

    // BCE partial sum. Clamp-before-multiply: p=0,g=0 slots contribute exactly 0,
    // so inactive-lane zero fills and the px/gx "extra" term need no branches.
    float s = 0.0f;
    {
        const float pe[17] = {p0.x,p0.y,p0.z,p0.w, p1.x,p1.y,p1.z,p1.w,
                              p2.x,p2.y,p2.z,p2.w, p3.x,p3.y,p3.z,p3.w, px};
        const float ge[17] = {g0.x,g0.y,g0.z,g0.w, g1.x,g1.y,g1.z,g1.w,
                              g2.x,g2.y,g2.z,g2.w, g3.x,g3.y,g3.z,g3.w, gx};
        #pragma unroll
        for (int q = 0; q < 17; ++q) {
            const float lp = fmaxf(__logf(pe[q]),        -100.0f);
            const float l1 = fmaxf(__logf(1.0f - pe[q]), -100.0f);
            s -= l1 + ge[q] * (lp - l1);   // bce = -(l1 + g*(lp-l1))
        }
    }

    float* const orow_p   = out + 1 + (size_t)r * NQ;
    float* const orow_g   = out + 1 + (size_t)NROWS * NQ + (size_t)r * NQ;
    float* const out_mask = out + 1 + 2 * (size_t)NROWS * NQ;

    // Aligned body stores (orow+3 is 16B-aligned), straight from registers.
    *(float4*)(orow_p + 3 + 4 * lane)         = make_float4(p0.x*m, p0.y*m, p0.z*m, p0.w*m);
    *(float4*)(orow_p + 3 + 4 * (lane + 64))  = make_float4(p1.x*m, p1.y*m, p1.z*m, p1.w*m);
    *(float4*)(orow_p + 3 + 4 * (lane + 128)) = make_float4(p2.x*m, p2.y*m, p2.z*m, p2.w*m);
    if (f3)
        *(float4*)(orow_p + 3 + 4 * (lane + 192)) = make_float4(p3.x*m, p3.y*m, p3.z*m, p3.w*m);

    *(float4*)(orow_g + 3 + 4 * lane)         = make_float4(g0.x*m, g0.y*m, g0.z*m, g0.w*m);
    *(float4*)(orow_g + 3 + 4 * (lane + 64))  = make_float4(g1.x*m, g1.y*m, g1.z*m, g1.w*m);
    *(float4*)(orow_g + 3 + 4 * (lane + 128)) = make_float4(g2.x*m, g2.y*m, g2.z*m, g2.w*m);
    if (f3)
        *(float4*)(orow_g + 3 + 4 * (lane + 192)) = make_float4(g3.x*m, g3.y*m, g3.z*m, g3.w*m);

    if (e >= 0) {                              // head e0..2 (lanes 58..60), tail e999 (lane 57)
        orow_p[e] = px * m;
        orow_g[e] = gx * m;
    }

    // wave-level sum reduction (lane 0 gets the row total)
    #pragma unroll
    for (int off = 32; off > 0; off >>= 1) s += __shfl_down(s, off);

    if (lane == 0) {
        out_mask[r] = m;
        if (bm) {
            atomicAdd(&ws[b], s);
            atomicAdd(&ws[BATCHN + b], 1.0f);
        }
    }
}

__global__ __launch_bounds__(256) void final_kernel(
    float* __restrict__ out, const float* __restrict__ ws)
{
    const int b = threadIdx.x;  // 0..255 (one per batch element)
    // cnt >= 1 guaranteed: batch[:,1,0] == 1 so t=0 row is always masked
    float per = ws[b] / (ws[BATCHN + b] * (float)NQ);

    #pragma unroll
    for (int off = 32; off > 0; off >>= 1) per += __shfl_down(per, off);

    __shared__ float ssum[4];
    const int lane = b & 63, wid = b >> 6;
    if (lane == 0) ssum[wid] = per;
    __syncthreads();
    if (b == 0) out[0] = ssum[0] + ssum[1] + ssum[2] + ssum[3];
}

extern "C" void kernel_launch(void* const* d_in, const int* in_sizes, int n_in,
                              void* d_out, int out_size, void* d_ws, size_t ws_size,
                              hipStream_t stream) {
    const float* pred  = (const float*)d_in[0];
    const float* batch = (const float*)d_in[1];
    float* out = (float*)d_out;
    float* ws  = (float*)d_ws;

    zero_ws_kernel<<<1, 512, 0, stream>>>(ws);
    main_kernel<<<NBLOCKS, 256, 0, stream>>>(pred, batch, out, ws);
    final_kernel<<<1, 256, 0, stream>>>(out, ws);
}

// Round 7
// 649.697 us; speedup vs baseline: 1.0776x; 1.0776x over previous
//
#include <hip/hip_runtime.h>

#define BATCHN 256
#define TSTEPS 199          // MAX_STEP - 1
#define NQ     1000
#define NROWS  (BATCHN * TSTEPS)   // 50944
#define RPB    4                   // rows (waves) per block
#define NBLOCKS (NROWS / RPB)      // 12736, exact

typedef float f4v __attribute__((ext_vector_type(4)));

// Unaligned (4B-aligned) 16B vector load.
__device__ __forceinline__ f4v loadu4(const float* p) {
    f4v v; __builtin_memcpy(&v, p, 16); return v;
}

// ---- fallback (small ws) path helpers: ws[0..255]=sum, ws[256..511]=cnt ----
__global__ void zero_ws_kernel(float* __restrict__ ws) {
    int i = threadIdx.x;
    if (i < 2 * BATCHN) ws[i] = 0.0f;
}

// One wave per row, shifted loads (body groups output-aligned: elements 3+4*kp..6+4*kp,
// kp = lane+64j, kp=0..248; head e0..2 / tail e999 on lanes 57..60). Wave-uniform
// early-out on unmasked rows skips the pred read and all BCE compute; masked path
// has m==1 so stores are straight register copies.
// ROWSUM=true: per-row sums to ws[r] (no atomics, no ws zeroing). false: atomic path.
template<bool ROWSUM>
__global__ __launch_bounds__(256) void main_kernel(
    const float* __restrict__ pred,
    const float* __restrict__ batch,
    float* __restrict__ out,
    float* __restrict__ ws)
{
    const int wid  = threadIdx.x >> 6;
    const int lane = threadIdx.x & 63;
    const int r = blockIdx.x * RPB + wid;      // row 0..NROWS-1
    const int b = r / TSTEPS;
    const int t = r - b * TSTEPS;

    const float* prow = pred + (size_t)r * NQ;
    const float* grow = batch + ((size_t)b * 200 + t + 1) * NQ;

    const bool f3 = lane < 57;                 // kp3 = lane+192 <= 248
    const int e = (lane == 57) ? 999 : (lane >= 58 && lane < 61) ? (lane - 58) : -1;
    const f4v z = {0.f, 0.f, 0.f, 0.f};

    f4v g0 = loadu4(grow + 3 + 4 * lane);
    f4v g1 = loadu4(grow + 3 + 4 * (lane + 64));
    f4v g2 = loadu4(grow + 3 + 4 * (lane + 128));
    f4v g3 = f3 ? loadu4(grow + 3 + 4 * (lane + 192)) : z;
    float gx = (e >= 0) ? grow[e] : 0.0f;

    int any = (g0.x == 1.0f) | (g0.y == 1.0f) | (g0.z == 1.0f) | (g0.w == 1.0f)
            | (g1.x == 1.0f) | (g1.y == 1.0f) | (g1.z == 1.0f) | (g1.w == 1.0f)
            | (g2.x == 1.0f) | (g2.y == 1.0f) | (g2.z == 1.0f) | (g2.w == 1.0f)
            | (g3.x == 1.0f) | (g3.y == 1.0f) | (g3.z == 1.0f) | (g3.w == 1.0f)
            | (gx   == 1.0f);
    const unsigned long long bm = __ballot(any);

    float* const orow_p   = out + 1 + (size_t)r * NQ;
    float* const orow_g   = out + 1 + (size_t)NROWS * NQ + (size_t)r * NQ;
    float* const out_mask = out + 1 + 2 * (size_t)NROWS * NQ;

    if (!bm) {
        // Unmasked row (wave-uniform): everything is zero; pred never read.
        *(f4v*)(orow_p + 3 + 4 * lane)         = z;
        *(f4v*)(orow_p + 3 + 4 * (lane + 64))  = z;
        *(f4v*)(orow_p + 3 + 4 * (lane + 128)) = z;
        if (f3) *(f4v*)(orow_p + 3 + 4 * (lane + 192)) = z;
        *(f4v*)(orow_g + 3 + 4 * lane)         = z;
        *(f4v*)(orow_g + 3 + 4 * (lane + 64))  = z;
        *(f4v*)(orow_g + 3 + 4 * (lane + 128)) = z;
        if (f3) *(f4v*)(orow_g + 3 + 4 * (lane + 192)) = z;
        if (e >= 0) { orow_p[e] = 0.0f; orow_g[e] = 0.0f; }
        if (lane == 0) {
            out_mask[r] = 0.0f;
            if (ROWSUM) ws[r] = 0.0f;
        }
        return;
    }

    // Masked row: m == 1, stores are raw copies.
    f4v p0 = loadu4(prow + 3 + 4 * lane);
    f4v p1 = loadu4(prow + 3 + 4 * (lane + 64));
    f4v p2 = loadu4(prow + 3 + 4 * (lane + 128));
    f4v p3 = f3 ? loadu4(prow + 3 + 4 * (lane + 192)) : z;
    float px = (e >= 0) ? prow[e] : 0.0f;

    *(f4v*)(orow_p + 3 + 4 * lane)         = p0;
    *(f4v*)(orow_p + 3 + 4 * (lane + 64))  = p1;
    *(f4v*)(orow_p + 3 + 4 * (lane + 128)) = p2;
    if (f3) *(f4v*)(orow_p + 3 + 4 * (lane + 192)) = p3;
    *(f4v*)(orow_g + 3 + 4 * lane)         = g0;
    *(f4v*)(orow_g + 3 + 4 * (lane + 64))  = g1;
    *(f4v*)(orow_g + 3 + 4 * (lane + 128)) = g2;
    if (f3) *(f4v*)(orow_g + 3 + 4 * (lane + 192)) = g3;
    if (e >= 0) { orow_p[e] = px; orow_g[e] = gx; }

    // BCE partial sum. Clamp-before-multiply: p=0,g=0 fill slots contribute exactly 0.
    float s = 0.0f;
    {
        const float pe[17] = {p0.x,p0.y,p0.z,p0.w, p1.x,p1.y,p1.z,p1.w,
                              p2.x,p2.y,p2.z,p2.w, p3.x,p3.y,p3.z,p3.w, px};
        const float ge[17] = {g0.x,g0.y,g0.z,g0.w, g1.x,g1.y,g1.z,g1.w,
                              g2.x,g2.y,g2.z,g2.w, g3.x,g3.y,g3.z,g3.w, gx};
        #pragma unroll
        for (int q = 0; q < 17; ++q) {
            const float lp = fmaxf(__logf(pe[q]),        -100.0f);
            const float l1 = fmaxf(__logf(1.0f - pe[q]), -100.0f);
            s -= l1 + ge[q] * (lp - l1);   // bce = -(l1 + g*(lp-l1))
        }
    }

    #pragma unroll
    for (int off = 32; off > 0; off >>= 1) s += __shfl_down(s, off);

    if (lane == 0) {
        out_mask[r] = 1.0f;
        if (ROWSUM) {
            ws[r] = s;
        } else {
            atomicAdd(&ws[b], s);
            atomicAdd(&ws[BATCHN + b], 1.0f);
        }
    }
}

// ROWSUM path: fold 199 row sums + masks -> per-batch mean, into ws[NROWS + b].
__global__ __launch_bounds__(256) void reduce_kernel(
    const float* __restrict__ out, float* __restrict__ ws)
{
    const int b = blockIdx.x;          // 0..255
    const int i = threadIdx.x;         // 0..255
    const float* out_mask = out + 1 + 2 * (size_t)NROWS * NQ;

    float v = 0.0f, c = 0.0f;
    if (i < TSTEPS) {
        const int r = b * TSTEPS + i;
        v = ws[r];
        c = out_mask[r];
    }
    #pragma unroll
    for (int off = 32; off > 0; off >>= 1) {
        v += __shfl_down(v, off);
        c += __shfl_down(c, off);
    }
    __shared__ float sv[4], sc[4];
    const int lane = i & 63, w = i >> 6;
    if (lane == 0) { sv[w] = v; sc[w] = c; }
    __syncthreads();
    if (i == 0) {
        const float vt = sv[0] + sv[1] + sv[2] + sv[3];
        const float ct = sc[0] + sc[1] + sc[2] + sc[3];   // >= 1 (t=0 always masked)
        ws[NROWS + b] = vt / (ct * (float)NQ);
    }
}

__global__ __launch_bounds__(256) void final2_kernel(
    float* __restrict__ out, const float* __restrict__ ws)
{
    const int b = threadIdx.x;
    float per = ws[NROWS + b];
    #pragma unroll
    for (int off = 32; off > 0; off >>= 1) per += __shfl_down(per, off);
    __shared__ float ssum[4];
    const int lane = b & 63, w = b >> 6;
    if (lane == 0) ssum[w] = per;
    __syncthreads();
    if (b == 0) out[0] = ssum[0] + ssum[1] + ssum[2] + ssum[3];
}

// fallback path final (atomic ws layout)
__global__ __launch_bounds__(256) void final_kernel(
    float* __restrict__ out, const float* __restrict__ ws)
{
    const int b = threadIdx.x;
    float per = ws[b] / (ws[BATCHN + b] * (float)NQ);
    #pragma unroll
    for (int off = 32; off > 0; off >>= 1) per += __shfl_down(per, off);
    __shared__ float ssum[4];
    const int lane = b & 63, w = b >> 6;
    if (lane == 0) ssum[w] = per;
    __syncthreads();
    if (b == 0) out[0] = ssum[0] + ssum[1] + ssum[2] + ssum[3];
}

extern "C" void kernel_launch(void* const* d_in, const int* in_sizes, int n_in,
                              void* d_out, int out_size, void* d_ws, size_t ws_size,
                              hipStream_t stream) {
    const float* pred  = (const float*)d_in[0];
    const float* batch = (const float*)d_in[1];
    float* out = (float*)d_out;
    float* ws  = (float*)d_ws;

    if (ws_size >= (size_t)(NROWS + BATCHN) * sizeof(float)) {
        // atomic-free path: per-row sums in ws, two-stage reduction
        main_kernel<true><<<NBLOCKS, 256, 0, stream>>>(pred, batch, out, ws);
        reduce_kernel<<<BATCHN, 256, 0, stream>>>(out, ws);
        final2_kernel<<<1, 256, 0, stream>>>(out, ws);
    } else {
        zero_ws_kernel<<<1, 512, 0, stream>>>(ws);
        main_kernel<false><<<NBLOCKS, 256, 0, stream>>>(pred, batch, out, ws);
        final_kernel<<<1, 256, 0, stream>>>(out, ws);
    }
}